// Round 2
// baseline (116013.940 us; speedup 1.0000x reference)
//
#include <hip/hip_runtime.h>

// ---- problem constants ----
constexpr int SQ = 8192;   // sequence length
constexpr int HD = 256;    // hidden size H
constexpr int NG = 1024;   // 4H (gate width)

typedef __fp16 h2 __attribute__((ext_vector_type(2)));
typedef unsigned int uint;

__device__ __forceinline__ float sigm_f(float x) {
  float e = __builtin_amdgcn_exp2f(-1.4426950408889634f * x);
  return __builtin_amdgcn_rcpf(1.0f + e);
}
__device__ __forceinline__ float tanh_f(float x) {
  float e = __builtin_amdgcn_exp2f(2.885390081777927f * x);
  return 1.0f - 2.0f * __builtin_amdgcn_rcpf(1.0f + e);
}

// =====================================================================
// xp GEMM: out[d][m][n] = sum_k A[m][k] * W[d][k][n] + bias[d][n]
// =====================================================================
__global__ __launch_bounds__(256) void gemm_xp(const float* __restrict__ A, int K,
                                               const float* __restrict__ W,
                                               const float* __restrict__ bias,
                                               float* __restrict__ out) {
  __shared__ float Al[16][64];  // [k][m]
  __shared__ float Bl[16][64];  // [k][n]
  const int tid = threadIdx.x;
  const int bm = blockIdx.x * 64;
  const int d  = blockIdx.y >> 4;
  const int bn = (blockIdx.y & 15) * 64;
  const float* Wd = W + (size_t)d * K * NG;
  const float* bd = bias + (size_t)d * NG;
  float* outd = out + (size_t)d * SQ * NG;

  const int m4 = (tid >> 4) << 2;
  const int n4 = (tid & 15) << 2;
  const int am = tid >> 2, ak = (tid & 3) << 2;
  const int bk = tid >> 4, bnn = (tid & 15) << 2;

  float acc[4][4] = {};
  for (int kt = 0; kt < K; kt += 16) {
    float4 av = *(const float4*)(A + (size_t)(bm + am) * K + kt + ak);
    float4 bv = *(const float4*)(Wd + (size_t)(kt + bk) * NG + bn + bnn);
    __syncthreads();
    Al[ak + 0][am] = av.x;
    Al[ak + 1][am] = av.y;
    Al[ak + 2][am] = av.z;
    Al[ak + 3][am] = av.w;
    *(float4*)&Bl[bk][bnn] = bv;
    __syncthreads();
#pragma unroll
    for (int k = 0; k < 16; ++k) {
      float4 a = *(const float4*)&Al[k][m4];
      float4 b = *(const float4*)&Bl[k][n4];
      float ar[4] = {a.x, a.y, a.z, a.w};
      float br[4] = {b.x, b.y, b.z, b.w};
#pragma unroll
      for (int i = 0; i < 4; ++i)
#pragma unroll
        for (int jj = 0; jj < 4; ++jj)
          acc[i][jj] = fmaf(ar[i], br[jj], acc[i][jj]);
    }
  }
#pragma unroll
  for (int i = 0; i < 4; ++i) {
    float4 o;
    o.x = acc[i][0] + bd[bn + n4 + 0];
    o.y = acc[i][1] + bd[bn + n4 + 1];
    o.z = acc[i][2] + bd[bn + n4 + 2];
    o.w = acc[i][3] + bd[bn + n4 + 3];
    *(float4*)(outd + (size_t)(bm + m4 + i) * NG + bn + n4) = o;
  }
}

__global__ void init_flags(int* flags) {
  if (threadIdx.x < 4) flags[threadIdx.x] = 0;
}

// =====================================================================
// LSTM recurrence, 2 CUs per direction (gate-split).
// grid = 4 blocks: b -> d = b>>1 (direction), g = b&1 (gate half).
// Block (d,g) owns global gate columns [g*512, g*512+512): g=0 -> {i,f},
// g=1 -> {g,o}. Thread j: wave w=j>>6, lane l=j&63.
//   local col cl = w*32 + (l&31)  (0..511), row half s = l>>5.
// Weights: rows [s*128, s*128+128) of col gc -> 64 h2 regs (fits: 256KB/CU).
// Per step: 64 fdot2 + 16 broadcast ds_read_b128 of h; pair-reduce via
// shfl_xor(32); activation; publish own 2 gates (2KB) to gx via agent-scope
// atomics + flag; both blocks redundantly update c,h (replicated state).
// Parity double-buffer on gx; flags monotonic via epoch = layer*SQ.
// =====================================================================
__global__ __launch_bounds__(1024, 4) void lstm_rec2(const float* __restrict__ Whh,
                                                     const float* __restrict__ xp,
                                                     float* __restrict__ obuf,
                                                     float* gx, int* flags, int ep) {
  __shared__ float glds[512];   // own gates
  __shared__ uint4 hlds[32];    // h packed f16x2: dword r = (h[2r],h[2r+1])
  const int b = blockIdx.x;
  const int d = b >> 1, g = b & 1;
  const int j = threadIdx.x;
  const int w = j >> 6, l = j & 63;
  const int cl = w * 32 + (l & 31);       // local col 0..511
  const int s  = l >> 5;                  // row half (uniform per 32-lane half)
  const int gc = g * 512 + cl;            // global gate col
  const float* W   = Whh + (size_t)d * HD * NG;
  const float* xpd = xp + (size_t)d * SQ * NG;
  float* gx_self  = gx + ((size_t)(d * 2 + g)) * 2 * 512;
  float* gx_other = gx + ((size_t)(d * 2 + (1 - g))) * 2 * 512;
  int* flag_self  = flags + d * 2 + g;
  int* flag_other = flags + d * 2 + (1 - g);

  // ---- one-time weight load: 64 h2 = rows [s*128, s*128+128) of col gc ----
  h2 wreg[64];
  const float* Wc = W + (size_t)(s * 128) * NG + gc;
#pragma unroll
  for (int k = 0; k < 64; ++k)
    wreg[k] = __builtin_amdgcn_cvt_pkrtz(Wc[(size_t)(2 * k) * NG],
                                         Wc[(size_t)(2 * k + 1) * NG]);

  if (j < 32) hlds[j] = make_uint4(0u, 0u, 0u, 0u);
  __syncthreads();

  const int fwd = (d == 0) ? 1 : 0;
  int t = fwd ? 0 : SQ - 1;
  const int dt = fwd ? 1 : -1;
  const int hbase = s * 16;
  const bool is_tanh = (g == 1) && (cl < 256);   // global gate 2 (g-gate)
  float cc = 0.0f;
  float xp_cur = xpd[(size_t)t * NG + gc];

  for (int step = 0; step < SQ; ++step) {
    float xp_next = (step + 1 < SQ) ? xpd[(size_t)(t + dt) * NG + gc] : 0.0f;

    float a0 = 0.0f, a1 = 0.0f;
#pragma unroll
    for (int q = 0; q < 16; ++q) {
      uint4 hq = hlds[hbase + q];         // broadcast (uniform per 32-lane half)
      a0 = __builtin_amdgcn_fdot2(wreg[4 * q + 0], __builtin_bit_cast(h2, hq.x), a0, false);
      a1 = __builtin_amdgcn_fdot2(wreg[4 * q + 1], __builtin_bit_cast(h2, hq.y), a1, false);
      a0 = __builtin_amdgcn_fdot2(wreg[4 * q + 2], __builtin_bit_cast(h2, hq.z), a0, false);
      a1 = __builtin_amdgcn_fdot2(wreg[4 * q + 3], __builtin_bit_cast(h2, hq.w), a1, false);
    }
    float part = a0 + a1;
    float full = part + __shfl_xor(part, 32);   // combine row halves
    float pre  = full + xp_cur;
    float act  = is_tanh ? tanh_f(pre) : sigm_f(pre);

    float* gxs = gx_self + (step & 1) * 512;
    if (l < 32) {
      glds[cl] = act;
      __hip_atomic_store(gxs + cl, act, __ATOMIC_RELAXED, __HIP_MEMORY_SCOPE_AGENT);
    }
    __syncthreads();   // B1: glds visible; gx stores drained (vmcnt before barrier)

    if (j < 256) {
      const int target = ep + step + 1;
      if (j == 0)
        __hip_atomic_store(flag_self, target, __ATOMIC_RELEASE, __HIP_MEMORY_SCOPE_AGENT);
      while (__hip_atomic_load(flag_other, __ATOMIC_ACQUIRE, __HIP_MEMORY_SCOPE_AGENT) < target) {}
      const float* gxo = gx_other + (step & 1) * 512;
      float o0 = __hip_atomic_load(gxo + j,       __ATOMIC_RELAXED, __HIP_MEMORY_SCOPE_AGENT);
      float o1 = __hip_atomic_load(gxo + 256 + j, __ATOMIC_RELAXED, __HIP_MEMORY_SCOPE_AGENT);
      float iv, fv, gv, ov;
      if (g == 0) { iv = glds[j]; fv = glds[256 + j]; gv = o0; ov = o1; }
      else        { gv = glds[j]; ov = glds[256 + j]; iv = o0; fv = o1; }
      cc = fv * cc + iv * gv;
      float hv = ov * tanh_f(cc);
      if (g == 0) obuf[(size_t)t * 512 + (d << 8) + j] = hv;
      float hn = __shfl_down(hv, 1);
      if (!(j & 1))
        ((uint*)hlds)[j >> 1] = __builtin_bit_cast(uint, __builtin_amdgcn_cvt_pkrtz(hv, hn));
    }
    __syncthreads();   // B2: hlds ready for next step
    xp_cur = xp_next;
    t += dt;
  }
}

// =====================================================================
// classifier head
// =====================================================================
__global__ void cls_k(const float* __restrict__ buf, const float* __restrict__ w1,
                      const float* __restrict__ b1, const float* __restrict__ w2,
                      const float* __restrict__ b2, float* __restrict__ out) {
  __shared__ float feat[512];
  __shared__ float hid[32];
  const int t = threadIdx.x;
  feat[t] = (t < 256) ? buf[(size_t)(SQ - 1) * 512 + t] : buf[t];
  __syncthreads();
  if (t < 32) {
    float a = b1[t];
    for (int k = 0; k < 512; ++k) a = fmaf(feat[k], w1[k * 32 + t], a);
    hid[t] = a;
  }
  __syncthreads();
  if (t < 2) {
    float a = b2[t];
    for (int k = 0; k < 32; ++k) a = fmaf(hid[k], w2[k * 2 + t], a);
    out[t] = a;
  }
}

// =====================================================================
extern "C" void kernel_launch(void* const* d_in, const int* in_sizes, int n_in,
                              void* d_out, int out_size, void* d_ws, size_t ws_size,
                              hipStream_t stream) {
  const float* x     = (const float*)d_in[0];
  const float* w_ih0 = (const float*)d_in[1];
  const float* w_hh0 = (const float*)d_in[2];
  const float* b0    = (const float*)d_in[3];
  const float* w_ih  = (const float*)d_in[4];
  const float* w_hh  = (const float*)d_in[5];
  const float* b     = (const float*)d_in[6];
  const float* w1    = (const float*)d_in[7];
  const float* b1    = (const float*)d_in[8];
  const float* w2    = (const float*)d_in[9];
  const float* b2    = (const float*)d_in[10];

  float* xp   = (float*)d_ws;                       // [2][SQ][NG] = 64MB
  float* bufA = xp + (size_t)2 * SQ * NG;           // [SQ][512]   = 16MB
  float* bufB = bufA + (size_t)SQ * 512;            // [SQ][512]   = 16MB
  float* gx   = bufB + (size_t)SQ * 512;            // [2][2][2][512] = 16KB
  int*   flags = (int*)(gx + 2 * 2 * 2 * 512);      // [4]

  const dim3 ggrid(SQ / 64, 32);

  init_flags<<<1, 64, 0, stream>>>(flags);

  // layer 0
  gemm_xp<<<ggrid, 256, 0, stream>>>(x, 1024, w_ih0, b0, xp);
  lstm_rec2<<<4, 1024, 0, stream>>>(w_hh0, xp, bufA, gx, flags, 0 * SQ);

  // layers 1..4
  float* cur = bufA;
  float* nxt = bufB;
  for (int lyr = 0; lyr < 4; ++lyr) {
    gemm_xp<<<ggrid, 256, 0, stream>>>(cur, 512, w_ih + (size_t)lyr * 2 * 512 * 1024,
                                       b + (size_t)lyr * 2 * 1024, xp);
    lstm_rec2<<<4, 1024, 0, stream>>>(w_hh + (size_t)lyr * 2 * 256 * 1024, xp, nxt,
                                      gx, flags, (lyr + 1) * SQ);
    float* tmp = cur; cur = nxt; nxt = tmp;
  }

  cls_k<<<1, 512, 0, stream>>>(cur, w1, b1, w2, b2, (float*)d_out);
}

// Round 3
// 71642.853 us; speedup vs baseline: 1.6193x; 1.6193x over previous
//
#include <hip/hip_runtime.h>

// ---- problem constants ----
constexpr int SQ = 8192;   // sequence length
constexpr int HD = 256;    // hidden size H
constexpr int NG = 1024;   // 4H (gate width)
constexpr int WSTR = 36;   // wlds per-col stride in dwords (16B-aligned, bank-spread)

typedef __fp16 h2 __attribute__((ext_vector_type(2)));
typedef unsigned int uint;

__device__ __forceinline__ float sigm_f(float x) {
  float e = __builtin_amdgcn_exp2f(-1.4426950408889634f * x);
  return __builtin_amdgcn_rcpf(1.0f + e);
}
__device__ __forceinline__ float tanh_f(float x) {
  float e = __builtin_amdgcn_exp2f(2.885390081777927f * x);
  return 1.0f - 2.0f * __builtin_amdgcn_rcpf(1.0f + e);
}
__device__ __forceinline__ h2 bch2(uint v) { return __builtin_bit_cast(h2, v); }

// =====================================================================
// xp GEMM: out[d][m][n] = sum_k A[m][k] * W[d][k][n] + bias[d][n]
// =====================================================================
__global__ __launch_bounds__(256) void gemm_xp(const float* __restrict__ A, int K,
                                               const float* __restrict__ W,
                                               const float* __restrict__ bias,
                                               float* __restrict__ out) {
  __shared__ float Al[16][64];  // [k][m]
  __shared__ float Bl[16][64];  // [k][n]
  const int tid = threadIdx.x;
  const int bm = blockIdx.x * 64;
  const int d  = blockIdx.y >> 4;
  const int bn = (blockIdx.y & 15) * 64;
  const float* Wd = W + (size_t)d * K * NG;
  const float* bd = bias + (size_t)d * NG;
  float* outd = out + (size_t)d * SQ * NG;

  const int m4 = (tid >> 4) << 2;
  const int n4 = (tid & 15) << 2;
  const int am = tid >> 2, ak = (tid & 3) << 2;
  const int bk = tid >> 4, bnn = (tid & 15) << 2;

  float acc[4][4] = {};
  for (int kt = 0; kt < K; kt += 16) {
    float4 av = *(const float4*)(A + (size_t)(bm + am) * K + kt + ak);
    float4 bv = *(const float4*)(Wd + (size_t)(kt + bk) * NG + bn + bnn);
    __syncthreads();
    Al[ak + 0][am] = av.x;
    Al[ak + 1][am] = av.y;
    Al[ak + 2][am] = av.z;
    Al[ak + 3][am] = av.w;
    *(float4*)&Bl[bk][bnn] = bv;
    __syncthreads();
#pragma unroll
    for (int k = 0; k < 16; ++k) {
      float4 a = *(const float4*)&Al[k][m4];
      float4 b = *(const float4*)&Bl[k][n4];
      float ar[4] = {a.x, a.y, a.z, a.w};
      float br[4] = {b.x, b.y, b.z, b.w};
#pragma unroll
      for (int i = 0; i < 4; ++i)
#pragma unroll
        for (int jj = 0; jj < 4; ++jj)
          acc[i][jj] = fmaf(ar[i], br[jj], acc[i][jj]);
    }
  }
#pragma unroll
  for (int i = 0; i < 4; ++i) {
    float4 o;
    o.x = acc[i][0] + bd[bn + n4 + 0];
    o.y = acc[i][1] + bd[bn + n4 + 1];
    o.z = acc[i][2] + bd[bn + n4 + 2];
    o.w = acc[i][3] + bd[bn + n4 + 3];
    *(float4*)(outd + (size_t)(bm + m4 + i) * NG + bn + n4) = o;
  }
}

// =====================================================================
// LSTM recurrence, 1 workgroup per direction, 512 threads (8 waves,
// 2 waves/SIMD -> 256 VGPR budget so weights stay in ARCH VGPRs).
// Thread (w=j>>6, li=l&31, s=l>>5) owns cols c_i = w*128 + 32*i + li
// (i=0..3) over K-half s (rows [s*128, s*128+128)).
//   rows [s*128, s*128+96): 48 h2/col x 4 cols = 192 VGPRs
//   rows [s*128+96, s*128+128): LDS (wldsu, 144KB, stride-36 cols)
// Per step: 256 fdot2, 16 broadcast h b128 reads, 16 w b128 reads,
// shfl_xor(32) K-combine, gates via glds[col] (coalesced), threads 0..255
// do the c/h update. All sync via 2 in-block barriers.
// =====================================================================
__global__ __launch_bounds__(512, 2) void lstm_rec3(const float* __restrict__ Whh,
                                                    const float* __restrict__ xp,
                                                    float* __restrict__ obuf) {
  __shared__ uint wldsu[1024 * WSTR];  // 144KB
  __shared__ float glds[1024];         // gate-major: index == global col
  __shared__ uint4 hlds[32];           // h packed f16x2: uint r = (h[2r],h[2r+1])
  const int d = blockIdx.x;
  const int j = threadIdx.x;
  const int w = j >> 6;
  const int l = j & 63;
  const int li = l & 31;
  const int s  = l >> 5;
  const float* W   = Whh + (size_t)d * HD * NG;
  const float* xpd = xp + (size_t)d * SQ * NG;
  const int cbase = w * 128 + li;       // col i = cbase + 32*i

  // ---- fill wlds: rows [ss*128+96, ss*128+128) as h2 pairs, per col ----
  for (int idx = j; idx < 1024 * 32; idx += 512) {
    const int c  = idx & 1023;
    const int q5 = idx >> 10;          // 0..31 : ss = q5>>4, p = q5&15
    const int ss = q5 >> 4, p = q5 & 15;
    const int r  = ss * 128 + 96 + 2 * p;
    wldsu[c * WSTR + q5] = __builtin_bit_cast(uint,
        __builtin_amdgcn_cvt_pkrtz(W[(size_t)r * NG + c], W[(size_t)(r + 1) * NG + c]));
  }

  // ---- register weights: rows [s*128, s*128+96) for 4 cols ----
  h2 wr[4][48];
#pragma unroll
  for (int i = 0; i < 4; ++i) {
    const float* Wc = W + (size_t)(s * 128) * NG + cbase + 32 * i;
#pragma unroll
    for (int k = 0; k < 48; ++k)
      wr[i][k] = __builtin_amdgcn_cvt_pkrtz(Wc[(size_t)(2 * k) * NG],
                                            Wc[(size_t)(2 * k + 1) * NG]);
  }

  if (j < 32) hlds[j] = make_uint4(0u, 0u, 0u, 0u);
  __syncthreads();

  const int fwd = (d == 0) ? 1 : 0;
  int t = fwd ? 0 : SQ - 1;
  const int dt = fwd ? 1 : -1;
  float cc = 0.0f;

  float xc[4], xn[4];
  if (s == 0) {
#pragma unroll
    for (int i = 0; i < 4; ++i) xc[i] = xpd[(size_t)t * NG + cbase + 32 * i];
  }

  for (int step = 0; step < SQ; ++step) {
    if (s == 0 && step + 1 < SQ) {
#pragma unroll
      for (int i = 0; i < 4; ++i) xn[i] = xpd[(size_t)(t + dt) * NG + cbase + 32 * i];
    }

    float acc[4] = {0.0f, 0.0f, 0.0f, 0.0f};
    const uint4* hb = hlds + s * 16;

#pragma unroll
    for (int q = 0; q < 12; ++q) {       // register-weight portion
      uint4 hq = hb[q];
      h2 hx = bch2(hq.x), hy = bch2(hq.y), hz = bch2(hq.z), hw = bch2(hq.w);
#pragma unroll
      for (int i = 0; i < 4; ++i) {
        acc[i] = __builtin_amdgcn_fdot2(wr[i][4 * q + 0], hx, acc[i], false);
        acc[i] = __builtin_amdgcn_fdot2(wr[i][4 * q + 1], hy, acc[i], false);
        acc[i] = __builtin_amdgcn_fdot2(wr[i][4 * q + 2], hz, acc[i], false);
        acc[i] = __builtin_amdgcn_fdot2(wr[i][4 * q + 3], hw, acc[i], false);
      }
    }
#pragma unroll
    for (int q = 12; q < 16; ++q) {      // LDS-weight portion
      uint4 hq = hb[q];
      h2 hx = bch2(hq.x), hy = bch2(hq.y), hz = bch2(hq.z), hw = bch2(hq.w);
      const int p4 = s * 16 + 4 * (q - 12);
#pragma unroll
      for (int i = 0; i < 4; ++i) {
        uint4 wq = *(const uint4*)&wldsu[(cbase + 32 * i) * WSTR + p4];
        acc[i] = __builtin_amdgcn_fdot2(bch2(wq.x), hx, acc[i], false);
        acc[i] = __builtin_amdgcn_fdot2(bch2(wq.y), hy, acc[i], false);
        acc[i] = __builtin_amdgcn_fdot2(bch2(wq.z), hz, acc[i], false);
        acc[i] = __builtin_amdgcn_fdot2(bch2(wq.w), hw, acc[i], false);
      }
    }

#pragma unroll
    for (int i = 0; i < 4; ++i) acc[i] += __shfl_xor(acc[i], 32);

    if (s == 0) {
#pragma unroll
      for (int i = 0; i < 4; ++i) {
        const int c = cbase + 32 * i;
        float pre = acc[i] + xc[i];
        float act = ((c >> 8) == 2) ? tanh_f(pre) : sigm_f(pre);
        glds[c] = act;                  // col == gate*256+unit: coalesced
      }
    }
    __syncthreads();   // B1: gates visible

    if (j < 256) {     // waves 0-3: state update for unit j
      float iv = glds[j];
      float fv = glds[256 + j];
      float gv = glds[512 + j];
      float ov = glds[768 + j];
      cc = fv * cc + iv * gv;
      float hv = ov * tanh_f(cc);
      obuf[(size_t)t * 512 + (d << 8) + j] = hv;
      float hn = __shfl_down(hv, 1);
      if (!(j & 1))
        ((uint*)hlds)[j >> 1] =
            __builtin_bit_cast(uint, __builtin_amdgcn_cvt_pkrtz(hv, hn));
    }
    __syncthreads();   // B2: h ready for next step

    if (s == 0) {
#pragma unroll
      for (int i = 0; i < 4; ++i) xc[i] = xn[i];
    }
    t += dt;
  }
}

// =====================================================================
// classifier head
// =====================================================================
__global__ void cls_k(const float* __restrict__ buf, const float* __restrict__ w1,
                      const float* __restrict__ b1, const float* __restrict__ w2,
                      const float* __restrict__ b2, float* __restrict__ out) {
  __shared__ float feat[512];
  __shared__ float hid[32];
  const int t = threadIdx.x;
  feat[t] = (t < 256) ? buf[(size_t)(SQ - 1) * 512 + t] : buf[t];
  __syncthreads();
  if (t < 32) {
    float a = b1[t];
    for (int k = 0; k < 512; ++k) a = fmaf(feat[k], w1[k * 32 + t], a);
    hid[t] = a;
  }
  __syncthreads();
  if (t < 2) {
    float a = b2[t];
    for (int k = 0; k < 32; ++k) a = fmaf(hid[k], w2[k * 2 + t], a);
    out[t] = a;
  }
}

// =====================================================================
extern "C" void kernel_launch(void* const* d_in, const int* in_sizes, int n_in,
                              void* d_out, int out_size, void* d_ws, size_t ws_size,
                              hipStream_t stream) {
  const float* x     = (const float*)d_in[0];
  const float* w_ih0 = (const float*)d_in[1];
  const float* w_hh0 = (const float*)d_in[2];
  const float* b0    = (const float*)d_in[3];
  const float* w_ih  = (const float*)d_in[4];
  const float* w_hh  = (const float*)d_in[5];
  const float* b     = (const float*)d_in[6];
  const float* w1    = (const float*)d_in[7];
  const float* b1    = (const float*)d_in[8];
  const float* w2    = (const float*)d_in[9];
  const float* b2    = (const float*)d_in[10];

  float* xp   = (float*)d_ws;                       // [2][SQ][NG] = 64MB
  float* bufA = xp + (size_t)2 * SQ * NG;           // [SQ][512]   = 16MB
  float* bufB = bufA + (size_t)SQ * 512;            // [SQ][512]   = 16MB

  const dim3 ggrid(SQ / 64, 32);

  // layer 0
  gemm_xp<<<ggrid, 256, 0, stream>>>(x, 1024, w_ih0, b0, xp);
  lstm_rec3<<<2, 512, 0, stream>>>(w_hh0, xp, bufA);

  // layers 1..4
  float* cur = bufA;
  float* nxt = bufB;
  for (int lyr = 0; lyr < 4; ++lyr) {
    gemm_xp<<<ggrid, 256, 0, stream>>>(cur, 512, w_ih + (size_t)lyr * 2 * 512 * 1024,
                                       b + (size_t)lyr * 2 * 1024, xp);
    lstm_rec3<<<2, 512, 0, stream>>>(w_hh + (size_t)lyr * 2 * 256 * 1024, xp, nxt);
    float* tmp = cur; cur = nxt; nxt = tmp;
  }

  cls_k<<<1, 512, 0, stream>>>(cur, w1, b1, w2, b2, (float*)d_out);
}